// Round 6
// baseline (50.159 us; speedup 1.0000x reference)
//
#include <hip/hip_runtime.h>
#include <cmath>

#define NROWS 4096
#define TLEN  1024
#define RPB   8            // rows per block
#define LT0   895
#define ST0   889
#define LTN   129
#define STN   135
#define PRV4R 1806         // float4 per row of pr = 129*56/4
#define PRV4B (RPB * PRV4R)   // 14448

__device__ __forceinline__ float sigmoidf_(float x) {
    return 1.0f / (1.0f + expf(-x));
}

__device__ __forceinline__ float f4c(const float4& v, int k) {
    switch (k & 3) { case 0: return v.x; case 1: return v.y; case 2: return v.z; default: return v.w; }
}

// One block = 8 rows x 32 chunks of 32 timesteps. Blocked parallel scan
// (LB recurrence linear 2x2; seasonal = 7 scalar lag-1 chains). Phase 3
// runs the true L/B chain once, saving e[] and sv[]=y-level and writing
// Lt/Tt tails to LDS inline; phase 5 is a cheap lag-1 sn chain with a tight
// homogeneous sm store burst; phase 6 is a pure coalesced pr drain.
__global__ __launch_bounds__(256, 4)
void es_fused(const float* __restrict__ query,
              const float* __restrict__ params,
              float* __restrict__ sm,
              float* __restrict__ diffs,
              float4* __restrict__ pr4)
{
    __shared__ float lds_P[RPB * 65];      // r*65 + 2k + b
    __shared__ float lds_start[RPB * 65];
    __shared__ float lds_q[RPB * 225];     // r*225 + k*7 + g (global phase)
    __shared__ float lds_dsum[RPB * 33];
    __shared__ float lds_par[RPB * 16];    // {L0,B0,ia,A10,A11,ic,is[7]}
    __shared__ float Ltl[RPB * 132];       // level  t=895..1023
    __shared__ float Ttl[RPB * 132];       // trend  t=895..1023
    __shared__ float Stl[RPB * 136];       // seas   t=889..1023

    const int tid = threadIdx.x;
    const int r = tid >> 5;          // local row 0..7
    const int k = tid & 31;          // chunk 0..31
    const int n = blockIdx.x * RPB + r;

    const float* pp = params + (size_t)n * 12;
    const float a  = sigmoidf_(pp[1]);
    const float b  = sigmoidf_(pp[3]);
    const float c  = pp[4];                   // raw (reference does NOT sigmoid)
    const float ia = 1.0f - a, ib = 1.0f - b, ic = 1.0f - c;

    // per-thread y chunk (32 floats in regs)
    float4 yv[8];
    {
        const float4* qv = reinterpret_cast<const float4*>(query + (size_t)n * TLEN + k * 32);
        #pragma unroll
        for (int i = 0; i < 8; ++i) yv[i] = qv[i];
    }

    // ---- phase 1: affine partial of LB chunk (zero init) ----
    {
        float L = 0.0f, B = 0.0f;
        #pragma unroll
        for (int j = 0; j < 32; ++j) {
            const float yy = f4c(yv[j >> 2], j);
            const float pred  = L + B;
            const float level = fmaf(a, yy, ia * pred);
            const float trend = fmaf(b, level - L, ib * B);
            L = level; B = trend;
        }
        lds_P[r * 65 + 2 * k]     = L;
        lds_P[r * 65 + 2 * k + 1] = B;
    }
    if (k == 0) {
        float* par = &lds_par[r * 16];
        par[0] = pp[0];                  // L0
        par[1] = pp[2];                  // B0
        par[2] = ia;                     // A00 = A01
        par[3] = -(a * b);               // A10
        par[4] = ib + b * ia;            // A11
        par[5] = ic;
        #pragma unroll
        for (int l = 0; l < 7; ++l) par[6 + l] = sigmoidf_(pp[5 + l]);
    }
    __syncthreads();

    // ---- phase 2: per-row serial scan of 32 chunk summaries (8 threads) ----
    if (tid < 8) {
        const float* par = &lds_par[tid * 16];
        float m00 = par[2], m01 = par[2], m10 = par[3], m11 = par[4];
        #pragma unroll
        for (int s = 0; s < 5; ++s) {    // M = A^32
            const float t00 = m00 * m00 + m01 * m10;
            const float t01 = m00 * m01 + m01 * m11;
            const float t10 = m10 * m00 + m11 * m10;
            const float t11 = m10 * m01 + m11 * m11;
            m00 = t00; m01 = t01; m10 = t10; m11 = t11;
        }
        float P0[32], P1[32];
        #pragma unroll
        for (int kk = 0; kk < 32; ++kk) {
            P0[kk] = lds_P[tid * 65 + 2 * kk];
            P1[kk] = lds_P[tid * 65 + 2 * kk + 1];
        }
        float s0 = par[0], s1 = par[1];
        #pragma unroll
        for (int kk = 0; kk < 32; ++kk) {
            lds_start[tid * 65 + 2 * kk]     = s0;
            lds_start[tid * 65 + 2 * kk + 1] = s1;
            const float t0 = m00 * s0 + m01 * s1 + P0[kk];
            const float t1 = m10 * s0 + m11 * s1 + P1[kk];
            s0 = t0; s1 = t1;
        }
    }
    __syncthreads();

    const float st0 = lds_start[r * 65 + 2 * k];
    const float st1 = lds_start[r * 65 + 2 * k + 1];

    // ---- phase 3: true chain once; save e[], sv[]; L/T tails -> LDS;
    //      seasonal partials; |dL| partial ----
    float e[32], sv[32];
    {
        float L = st0, B = st1, dsum = 0.0f;
        float q[7] = {0,0,0,0,0,0,0};
        #pragma unroll
        for (int j = 0; j < 32; ++j) {
            const float yy = f4c(yv[j >> 2], j);
            const float pred  = L + B;
            const float level = fmaf(a, yy, ia * pred);
            const float d     = level - L;
            dsum += fabsf(d);
            const float trend = fmaf(b, d, ib * B);
            const float ee    = yy - pred;
            e[j]  = ee;
            sv[j] = yy - level;
            q[j % 7] = fmaf(ic, q[j % 7], c * ee);
            const int tg = k * 32 + j;       // only k>=27 lanes ever hit this
            if (tg >= LT0) {
                Ltl[r * 132 + tg - LT0] = level;
                Ttl[r * 132 + tg - LT0] = trend;
            }
            L = level; B = trend;
        }
        const int kp = (4 * k) % 7;      // global phase of local slot 0
        #pragma unroll
        for (int l = 0; l < 7; ++l) {
            int g = kp + l; if (g >= 7) g -= 7;
            lds_q[r * 225 + k * 7 + g] = q[l];
        }
        lds_dsum[r * 33 + k] = dsum;
    }
    __syncthreads();

    // ---- phase 4: seasonal chain scan (56 threads) + diffs reduce (8) ----
    if (tid < 56) {
        const int rr = tid / 7, p = tid % 7;
        const float icc = lds_par[rr * 16 + 5];
        const float ic2 = icc * icc;
        const float ic4 = ic2 * ic2;
        const float ic5 = ic4 * icc;
        float v = lds_par[rr * 16 + 6 + p];
        float qq[32];
        #pragma unroll
        for (int kk = 0; kk < 32; ++kk) qq[kk] = lds_q[rr * 225 + kk * 7 + p];
        int l = p;
        #pragma unroll
        for (int kk = 0; kk < 32; ++kk) {
            const float m = (l < 4) ? ic5 : ic4;   // occurrences of phase in chunk
            const float nv = fmaf(m, v, qq[kk]);
            lds_q[rr * 225 + kk * 7 + p] = v;      // phase value entering chunk kk
            v = nv;
            l += 3; if (l >= 7) l -= 7;            // local slot of p in next chunk
        }
    } else if (tid < 64) {
        const int rr = tid - 56;
        float s = 0.0f;
        #pragma unroll
        for (int kk = 0; kk < 32; ++kk) s += lds_dsum[rr * 33 + kk];
        diffs[blockIdx.x * RPB + rr] = s * (1.0f / 1024.0f);
    }
    __syncthreads();

    // ---- phase 5: lag-1 sn chain from saved e[]; tight sm burst; S tails ----
    {
        float sg[7];
        const int kp = (4 * k) % 7;
        #pragma unroll
        for (int l = 0; l < 7; ++l) {
            int g = kp + l; if (g >= 7) g -= 7;
            sg[l] = lds_q[r * 225 + k * 7 + g];
        }
        float4 ov;
        float* smrow = sm + (size_t)n * TLEN + k * 32;
        #pragma unroll
        for (int j = 0; j < 32; ++j) {
            const float sn = fmaf(ic, sg[j % 7], c * e[j]);
            sg[j % 7] = sn;
            const float smv = sv[j] - sn;
            switch (j & 3) { case 0: ov.x = smv; break; case 1: ov.y = smv; break;
                             case 2: ov.z = smv; break; default: ov.w = smv; }
            if ((j & 3) == 3) *reinterpret_cast<float4*>(smrow + (j - 3)) = ov;
            const int tg = k * 32 + j;       // only k>=27 lanes ever hit this
            if (tg >= ST0) Stl[r * 136 + tg - ST0] = sn;
        }
    }
    __syncthreads();

    // ---- phase 6: pure pr drain from LDS tails (coalesced float4) ----
    {
        float4* prb = pr4 + (size_t)blockIdx.x * PRV4B;
        #pragma unroll 4
        for (int i = 0; i < 57; ++i) {
            const int q = i * 256 + tid;
            if (q < PRV4B) {
                const int row = q / PRV4R;
                const int rem = q - row * PRV4R;
                const int s   = rem / 14;
                const int h4  = rem - s * 14;
                const float L = Ltl[row * 132 + s];
                const float T = Ttl[row * 132 + s];
                const float* stp = &Stl[row * 136 + s];
                const int hb = h4 * 4;
                int m0 = hb % 7;
                int m1 = m0 + 1; if (m1 >= 7) m1 -= 7;
                int m2 = m0 + 2; if (m2 >= 7) m2 -= 7;
                int m3 = m0 + 3; if (m3 >= 7) m3 -= 7;
                float4 o;
                o.x = fmaf(T, (float)(hb + 1), L) + stp[m0];
                o.y = fmaf(T, (float)(hb + 2), L) + stp[m1];
                o.z = fmaf(T, (float)(hb + 3), L) + stp[m2];
                o.w = fmaf(T, (float)(hb + 4), L) + stp[m3];
                prb[q] = o;
            }
        }
    }
}

extern "C" void kernel_launch(void* const* d_in, const int* in_sizes, int n_in,
                              void* d_out, int out_size, void* d_ws, size_t ws_size,
                              hipStream_t stream) {
    const float* query  = (const float*)d_in[0];
    const float* params = (const float*)d_in[1];

    float* out   = (float*)d_out;
    float* sm    = out;                                  // 4096*1024
    float* pr    = out + (size_t)NROWS * TLEN;           // 4096*129*56
    float* diffs = pr  + (size_t)NROWS * 129 * 56;       // 4096

    hipLaunchKernelGGL(es_fused, dim3(NROWS / RPB), dim3(256), 0, stream,
                       query, params, sm, diffs, (float4*)pr);
}

// Round 7
// 37.338 us; speedup vs baseline: 1.3434x; 1.3434x over previous
//
#include <hip/hip_runtime.h>
#include <cmath>

#define NROWS 4096
#define TLEN  1024
#define RPB   8            // rows per block
#define LT0   895
#define ST0   889
#define LTN   129
#define STN   135
#define PRV4R 1806         // float4 per row of pr = 129*56/4
#define PRV4B (RPB * PRV4R)   // 14448

__device__ __forceinline__ float sigmoidf_(float x) {
    return 1.0f / (1.0f + expf(-x));
}

__device__ __forceinline__ float f4c(const float4& v, int k) {
    switch (k & 3) { case 0: return v.x; case 1: return v.y; case 2: return v.z; default: return v.w; }
}

// One block = 8 rows x 32 chunks of 32 timesteps. Blocked parallel scan
// (LB recurrence linear 2x2; seasonal = 7 scalar lag-1 chains). Phase 3
// runs the true L/B chain once saving e[] only (identities: y-level = ia*e,
// level = y - ia*e); k>=27 lanes rebuild L/T tails in a short masked loop;
// phase 5 is a lag-1 sn chain + homogeneous sm float4 burst; phase 6 is a
// pure coalesced pr drain from LDS tails.
__global__ __launch_bounds__(256, 2)
void es_fused(const float* __restrict__ query,
              const float* __restrict__ params,
              float* __restrict__ sm,
              float* __restrict__ diffs,
              float4* __restrict__ pr4)
{
    __shared__ float lds_P[RPB * 65];      // r*65 + 2k + b
    __shared__ float lds_start[RPB * 65];
    __shared__ float lds_q[RPB * 225];     // r*225 + k*7 + g (global phase)
    __shared__ float lds_dsum[RPB * 33];
    __shared__ float lds_par[RPB * 16];    // {L0,B0,ia,A10,A11,ic,is[7]}
    __shared__ float Ltl[RPB * 132];       // level  t=895..1023
    __shared__ float Ttl[RPB * 132];       // trend  t=895..1023
    __shared__ float Stl[RPB * 136];       // seas   t=889..1023

    const int tid = threadIdx.x;
    const int r = tid >> 5;          // local row 0..7
    const int k = tid & 31;          // chunk 0..31
    const int n = blockIdx.x * RPB + r;

    const float* pp = params + (size_t)n * 12;
    const float a  = sigmoidf_(pp[1]);
    const float b  = sigmoidf_(pp[3]);
    const float c  = pp[4];                   // raw (reference does NOT sigmoid)
    const float ia = 1.0f - a, ib = 1.0f - b, ic = 1.0f - c;

    // per-thread y chunk (32 floats in regs)
    float4 yv[8];
    {
        const float4* qv = reinterpret_cast<const float4*>(query + (size_t)n * TLEN + k * 32);
        #pragma unroll
        for (int i = 0; i < 8; ++i) yv[i] = qv[i];
    }

    // ---- phase 1: affine partial of LB chunk (zero init) ----
    {
        float L = 0.0f, B = 0.0f;
        #pragma unroll
        for (int j = 0; j < 32; ++j) {
            const float yy = f4c(yv[j >> 2], j);
            const float pred  = L + B;
            const float level = fmaf(a, yy, ia * pred);
            const float trend = fmaf(b, level - L, ib * B);
            L = level; B = trend;
        }
        lds_P[r * 65 + 2 * k]     = L;
        lds_P[r * 65 + 2 * k + 1] = B;
    }
    if (k == 0) {
        float* par = &lds_par[r * 16];
        par[0] = pp[0];                  // L0
        par[1] = pp[2];                  // B0
        par[2] = ia;                     // A00 = A01
        par[3] = -(a * b);               // A10
        par[4] = ib + b * ia;            // A11
        par[5] = ic;
        #pragma unroll
        for (int l = 0; l < 7; ++l) par[6 + l] = sigmoidf_(pp[5 + l]);
    }
    __syncthreads();

    // ---- phase 2: per-row serial scan of 32 chunk summaries (8 threads) ----
    if (tid < 8) {
        const float* par = &lds_par[tid * 16];
        float m00 = par[2], m01 = par[2], m10 = par[3], m11 = par[4];
        #pragma unroll
        for (int s = 0; s < 5; ++s) {    // M = A^32
            const float t00 = m00 * m00 + m01 * m10;
            const float t01 = m00 * m01 + m01 * m11;
            const float t10 = m10 * m00 + m11 * m10;
            const float t11 = m10 * m01 + m11 * m11;
            m00 = t00; m01 = t01; m10 = t10; m11 = t11;
        }
        float P0[32], P1[32];
        #pragma unroll
        for (int kk = 0; kk < 32; ++kk) {
            P0[kk] = lds_P[tid * 65 + 2 * kk];
            P1[kk] = lds_P[tid * 65 + 2 * kk + 1];
        }
        float s0 = par[0], s1 = par[1];
        #pragma unroll
        for (int kk = 0; kk < 32; ++kk) {
            lds_start[tid * 65 + 2 * kk]     = s0;
            lds_start[tid * 65 + 2 * kk + 1] = s1;
            const float t0 = m00 * s0 + m01 * s1 + P0[kk];
            const float t1 = m10 * s0 + m11 * s1 + P1[kk];
            s0 = t0; s1 = t1;
        }
    }
    __syncthreads();

    const float st0 = lds_start[r * 65 + 2 * k];
    const float st1 = lds_start[r * 65 + 2 * k + 1];

    // ---- phase 3: true chain once (clean); save e[]; partials; |dL| ----
    float e[32];
    {
        float L = st0, B = st1, dsum = 0.0f;
        float q[7] = {0,0,0,0,0,0,0};
        #pragma unroll
        for (int j = 0; j < 32; ++j) {
            const float yy = f4c(yv[j >> 2], j);
            const float pred  = L + B;
            const float level = fmaf(a, yy, ia * pred);
            const float d     = level - L;
            dsum += fabsf(d);
            const float trend = fmaf(b, d, ib * B);
            const float ee    = yy - pred;
            e[j] = ee;
            q[j % 7] = fmaf(ic, q[j % 7], c * ee);
            L = level; B = trend;
        }
        const int kp = (4 * k) % 7;      // global phase of local slot 0
        #pragma unroll
        for (int l = 0; l < 7; ++l) {
            int g = kp + l; if (g >= 7) g -= 7;
            lds_q[r * 225 + k * 7 + g] = q[l];
        }
        lds_dsum[r * 33 + k] = dsum;
    }

    // ---- phase 3b: k>=27 lanes rebuild level/trend tails -> LDS ----
    if (k >= 27) {
        float prevL = st0, Bv = st1;
        #pragma unroll
        for (int j = 0; j < 32; ++j) {
            const float level = f4c(yv[j >> 2], j) - ia * e[j];
            const float trend = fmaf(b, level - prevL, ib * Bv);
            const int tg = k * 32 + j;
            if (tg >= LT0) {
                Ltl[r * 132 + tg - LT0] = level;
                Ttl[r * 132 + tg - LT0] = trend;
            }
            prevL = level; Bv = trend;
        }
    }
    __syncthreads();

    // ---- phase 4: seasonal chain scan (56 threads) + diffs reduce (8) ----
    if (tid < 56) {
        const int rr = tid / 7, p = tid % 7;
        const float icc = lds_par[rr * 16 + 5];
        const float ic2 = icc * icc;
        const float ic4 = ic2 * ic2;
        const float ic5 = ic4 * icc;
        float v = lds_par[rr * 16 + 6 + p];
        float qq[32];
        #pragma unroll
        for (int kk = 0; kk < 32; ++kk) qq[kk] = lds_q[rr * 225 + kk * 7 + p];
        int l = p;
        #pragma unroll
        for (int kk = 0; kk < 32; ++kk) {
            const float m = (l < 4) ? ic5 : ic4;   // occurrences of phase in chunk
            const float nv = fmaf(m, v, qq[kk]);
            lds_q[rr * 225 + kk * 7 + p] = v;      // phase value entering chunk kk
            v = nv;
            l += 3; if (l >= 7) l -= 7;            // local slot of p in next chunk
        }
    } else if (tid < 64) {
        const int rr = tid - 56;
        float s = 0.0f;
        #pragma unroll
        for (int kk = 0; kk < 32; ++kk) s += lds_dsum[rr * 33 + kk];
        diffs[blockIdx.x * RPB + rr] = s * (1.0f / 1024.0f);
    }
    __syncthreads();

    // ---- phase 5: lag-1 sn chain; smv = ia*e - sn; tight sm burst; S tails ----
    {
        float sg[7];
        const int kp = (4 * k) % 7;
        #pragma unroll
        for (int l = 0; l < 7; ++l) {
            int g = kp + l; if (g >= 7) g -= 7;
            sg[l] = lds_q[r * 225 + k * 7 + g];
        }
        float4 ov;
        float* smrow = sm + (size_t)n * TLEN + k * 32;
        #pragma unroll
        for (int j = 0; j < 32; ++j) {
            const float sn = fmaf(ic, sg[j % 7], c * e[j]);
            sg[j % 7] = sn;
            const float smv = ia * e[j] - sn;
            switch (j & 3) { case 0: ov.x = smv; break; case 1: ov.y = smv; break;
                             case 2: ov.z = smv; break; default: ov.w = smv; }
            if ((j & 3) == 3) *reinterpret_cast<float4*>(smrow + (j - 3)) = ov;
            const int tg = k * 32 + j;       // only k>=27 lanes ever hit this
            if (tg >= ST0) Stl[r * 136 + tg - ST0] = sn;
        }
    }
    __syncthreads();

    // ---- phase 6: pure pr drain from LDS tails (coalesced float4) ----
    {
        float4* prb = pr4 + (size_t)blockIdx.x * PRV4B;
        #pragma unroll 4
        for (int i = 0; i < 57; ++i) {
            const int q = i * 256 + tid;
            if (q < PRV4B) {
                const int row = q / PRV4R;
                const int rem = q - row * PRV4R;
                const int s   = rem / 14;
                const int h4  = rem - s * 14;
                const float L = Ltl[row * 132 + s];
                const float T = Ttl[row * 132 + s];
                const float* stp = &Stl[row * 136 + s];
                const int hb = h4 * 4;
                int m0 = hb % 7;
                int m1 = m0 + 1; if (m1 >= 7) m1 -= 7;
                int m2 = m0 + 2; if (m2 >= 7) m2 -= 7;
                int m3 = m0 + 3; if (m3 >= 7) m3 -= 7;
                float4 o;
                o.x = fmaf(T, (float)(hb + 1), L) + stp[m0];
                o.y = fmaf(T, (float)(hb + 2), L) + stp[m1];
                o.z = fmaf(T, (float)(hb + 3), L) + stp[m2];
                o.w = fmaf(T, (float)(hb + 4), L) + stp[m3];
                prb[q] = o;
            }
        }
    }
}

extern "C" void kernel_launch(void* const* d_in, const int* in_sizes, int n_in,
                              void* d_out, int out_size, void* d_ws, size_t ws_size,
                              hipStream_t stream) {
    const float* query  = (const float*)d_in[0];
    const float* params = (const float*)d_in[1];

    float* out   = (float*)d_out;
    float* sm    = out;                                  // 4096*1024
    float* pr    = out + (size_t)NROWS * TLEN;           // 4096*129*56
    float* diffs = pr  + (size_t)NROWS * 129 * 56;       // 4096

    hipLaunchKernelGGL(es_fused, dim3(NROWS / RPB), dim3(256), 0, stream,
                       query, params, sm, diffs, (float4*)pr);
}

// Round 8
// 35.743 us; speedup vs baseline: 1.4033x; 1.0446x over previous
//
#include <hip/hip_runtime.h>
#include <cmath>

#define NROWS 4096
#define TLEN  1024
#define RPB   8            // rows per block
#define LT0   895
#define ST0   889
#define LTN   129
#define STN   135
#define PRV4R 1806         // float4 per row of pr = 129*56/4
#define PRV4B (RPB * PRV4R)   // 14448

__device__ __forceinline__ float sigmoidf_(float x) {
    return 1.0f / (1.0f + expf(-x));
}

__device__ __forceinline__ float f4c(const float4& v, int k) {
    switch (k & 3) { case 0: return v.x; case 1: return v.y; case 2: return v.z; default: return v.w; }
}

// One block = 8 rows x 32 chunks of 32 timesteps. Blocked parallel scan
// (LB recurrence linear 2x2; seasonal = 7 scalar lag-1 chains).
// All global traffic is full-wave contiguous: query is staged coalesced
// through a 32KB LDS tile (XOR-swizzled, conflict-free both sides), which is
// later reused to stage sm for a coalesced drain; pr drains from LDS tails
// with incremental index decomposition (no per-iter divisions).
__global__ __launch_bounds__(256, 2)
void es_fused(const float* __restrict__ query,
              const float* __restrict__ params,
              float* __restrict__ sm,
              float* __restrict__ diffs,
              float4* __restrict__ pr4)
{
    __shared__ float4 ystage[RPB * 256];   // 32KB: query in, then sm out
    __shared__ float lds_P[RPB * 65];      // r*65 + 2k + b
    __shared__ float lds_start[RPB * 65];
    __shared__ float lds_q[RPB * 225];     // r*225 + k*7 + g (global phase)
    __shared__ float lds_dsum[RPB * 33];
    __shared__ float lds_par[RPB * 16];    // {L0,B0,ia,A10,A11,ic,is[7]}
    __shared__ float Ltl[RPB * 132];       // level  t=895..1023
    __shared__ float Ttl[RPB * 132];       // trend  t=895..1023
    __shared__ float Stl[RPB * 136];       // seas   t=889..1023

    const int tid = threadIdx.x;
    const int r = tid >> 5;          // local row 0..7
    const int k = tid & 31;          // chunk 0..31
    const int base = blockIdx.x * RPB;
    const int n = base + r;

    // ---- phase 0: coalesced query stage -> LDS (swizzled) ----
    {
        const float4* qb = reinterpret_cast<const float4*>(query + (size_t)base * TLEN);
        const int cs = tid ^ ((tid >> 3) & 7);
        #pragma unroll
        for (int i = 0; i < 8; ++i)
            ystage[i * 256 + cs] = qb[i * 256 + tid];
    }

    const float* pp = params + (size_t)n * 12;
    const float a  = sigmoidf_(pp[1]);
    const float b  = sigmoidf_(pp[3]);
    const float c  = pp[4];                   // raw (reference does NOT sigmoid)
    const float ia = 1.0f - a, ib = 1.0f - b, ic = 1.0f - c;

    __syncthreads();

    // redistribute: per-thread y chunk (32 floats) from swizzled LDS
    float4 yv[8];
    {
        const int ksw = k & 7;
        #pragma unroll
        for (int i = 0; i < 8; ++i)
            yv[i] = ystage[r * 256 + ((k * 8 + i) ^ ksw)];
    }

    // ---- phase 1: affine partial of LB chunk (zero init) ----
    {
        float L = 0.0f, B = 0.0f;
        #pragma unroll
        for (int j = 0; j < 32; ++j) {
            const float yy = f4c(yv[j >> 2], j);
            const float pred  = L + B;
            const float level = fmaf(a, yy, ia * pred);
            const float trend = fmaf(b, level - L, ib * B);
            L = level; B = trend;
        }
        lds_P[r * 65 + 2 * k]     = L;
        lds_P[r * 65 + 2 * k + 1] = B;
    }
    if (k == 0) {
        float* par = &lds_par[r * 16];
        par[0] = pp[0];                  // L0
        par[1] = pp[2];                  // B0
        par[2] = ia;                     // A00 = A01
        par[3] = -(a * b);               // A10
        par[4] = ib + b * ia;            // A11
        par[5] = ic;
        #pragma unroll
        for (int l = 0; l < 7; ++l) par[6 + l] = sigmoidf_(pp[5 + l]);
    }
    __syncthreads();

    // ---- phase 2: per-row serial scan of 32 chunk summaries (8 threads) ----
    if (tid < 8) {
        const float* par = &lds_par[tid * 16];
        float m00 = par[2], m01 = par[2], m10 = par[3], m11 = par[4];
        #pragma unroll
        for (int s = 0; s < 5; ++s) {    // M = A^32
            const float t00 = m00 * m00 + m01 * m10;
            const float t01 = m00 * m01 + m01 * m11;
            const float t10 = m10 * m00 + m11 * m10;
            const float t11 = m10 * m01 + m11 * m11;
            m00 = t00; m01 = t01; m10 = t10; m11 = t11;
        }
        float P0[32], P1[32];
        #pragma unroll
        for (int kk = 0; kk < 32; ++kk) {
            P0[kk] = lds_P[tid * 65 + 2 * kk];
            P1[kk] = lds_P[tid * 65 + 2 * kk + 1];
        }
        float s0 = par[0], s1 = par[1];
        #pragma unroll
        for (int kk = 0; kk < 32; ++kk) {
            lds_start[tid * 65 + 2 * kk]     = s0;
            lds_start[tid * 65 + 2 * kk + 1] = s1;
            const float t0 = m00 * s0 + m01 * s1 + P0[kk];
            const float t1 = m10 * s0 + m11 * s1 + P1[kk];
            s0 = t0; s1 = t1;
        }
    }
    __syncthreads();

    const float st0 = lds_start[r * 65 + 2 * k];
    const float st1 = lds_start[r * 65 + 2 * k + 1];

    // ---- phase 3: true chain once (clean); save e[]; partials; |dL| ----
    float e[32];
    {
        float L = st0, B = st1, dsum = 0.0f;
        float q[7] = {0,0,0,0,0,0,0};
        #pragma unroll
        for (int j = 0; j < 32; ++j) {
            const float yy = f4c(yv[j >> 2], j);
            const float pred  = L + B;
            const float level = fmaf(a, yy, ia * pred);
            const float d     = level - L;
            dsum += fabsf(d);
            const float trend = fmaf(b, d, ib * B);
            const float ee    = yy - pred;
            e[j] = ee;
            q[j % 7] = fmaf(ic, q[j % 7], c * ee);
            L = level; B = trend;
        }
        const int kp = (4 * k) % 7;      // global phase of local slot 0
        #pragma unroll
        for (int l = 0; l < 7; ++l) {
            int g = kp + l; if (g >= 7) g -= 7;
            lds_q[r * 225 + k * 7 + g] = q[l];
        }
        lds_dsum[r * 33 + k] = dsum;
    }

    // ---- phase 3b: k>=27 lanes rebuild level/trend tails -> LDS ----
    if (k >= 27) {
        float prevL = st0, Bv = st1;
        #pragma unroll
        for (int j = 0; j < 32; ++j) {
            const float level = f4c(yv[j >> 2], j) - ia * e[j];
            const float trend = fmaf(b, level - prevL, ib * Bv);
            const int tg = k * 32 + j;
            if (tg >= LT0) {
                Ltl[r * 132 + tg - LT0] = level;
                Ttl[r * 132 + tg - LT0] = trend;
            }
            prevL = level; Bv = trend;
        }
    }
    __syncthreads();

    // ---- phase 4: seasonal chain scan (56 threads) + diffs reduce (8) ----
    if (tid < 56) {
        const int rr = tid / 7, p = tid % 7;
        const float icc = lds_par[rr * 16 + 5];
        const float ic2 = icc * icc;
        const float ic4 = ic2 * ic2;
        const float ic5 = ic4 * icc;
        float v = lds_par[rr * 16 + 6 + p];
        float qq[32];
        #pragma unroll
        for (int kk = 0; kk < 32; ++kk) qq[kk] = lds_q[rr * 225 + kk * 7 + p];
        int l = p;
        #pragma unroll
        for (int kk = 0; kk < 32; ++kk) {
            const float m = (l < 4) ? ic5 : ic4;   // occurrences of phase in chunk
            const float nv = fmaf(m, v, qq[kk]);
            lds_q[rr * 225 + kk * 7 + p] = v;      // phase value entering chunk kk
            v = nv;
            l += 3; if (l >= 7) l -= 7;            // local slot of p in next chunk
        }
    } else if (tid < 64) {
        const int rr = tid - 56;
        float s = 0.0f;
        #pragma unroll
        for (int kk = 0; kk < 32; ++kk) s += lds_dsum[rr * 33 + kk];
        diffs[blockIdx.x * RPB + rr] = s * (1.0f / 1024.0f);
    }
    __syncthreads();

    // ---- phase 5: lag-1 sn chain; smv = ia*e - sn -> swizzled LDS;
    //      e[] is overwritten with sn for the masked S-tail loop ----
    {
        float sg[7];
        const int kp = (4 * k) % 7;
        #pragma unroll
        for (int l = 0; l < 7; ++l) {
            int g = kp + l; if (g >= 7) g -= 7;
            sg[l] = lds_q[r * 225 + k * 7 + g];
        }
        const int ksw = k & 7;
        float4 ov;
        #pragma unroll
        for (int j = 0; j < 32; ++j) {
            const float sn = fmaf(ic, sg[j % 7], c * e[j]);
            sg[j % 7] = sn;
            const float smv = ia * e[j] - sn;
            e[j] = sn;
            switch (j & 3) { case 0: ov.x = smv; break; case 1: ov.y = smv; break;
                             case 2: ov.z = smv; break; default: ov.w = smv; }
            if ((j & 3) == 3)
                ystage[r * 256 + ((k * 8 + (j >> 2)) ^ ksw)] = ov;
        }
        if (k >= 27) {
            #pragma unroll
            for (int j = 0; j < 32; ++j) {
                const int tg = k * 32 + j;
                if (tg >= ST0) Stl[r * 136 + tg - ST0] = e[j];
            }
        }
    }
    __syncthreads();

    // ---- phase 6a: coalesced sm drain from LDS ----
    {
        float4* smb = reinterpret_cast<float4*>(sm + (size_t)base * TLEN);
        const int cs = tid ^ ((tid >> 3) & 7);
        #pragma unroll
        for (int i = 0; i < 8; ++i)
            smb[i * 256 + tid] = ystage[i * 256 + cs];
    }

    // ---- phase 6b: pure pr drain from LDS tails (incremental indexing) ----
    {
        float4* prb = pr4 + (size_t)blockIdx.x * PRV4B;
        int row = 0;
        int s   = tid / 14;
        int h4  = tid - s * 14;
        int m0  = (4 * h4) % 7;
        for (int i = 0; i < 57; ++i) {
            const int q = i * 256 + tid;
            if (q < PRV4B) {
                const float L = Ltl[row * 132 + s];
                const float T = Ttl[row * 132 + s];
                const float* stp = &Stl[row * 136 + s];
                int m1 = m0 + 1; if (m1 >= 7) m1 -= 7;
                int m2 = m1 + 1; if (m2 >= 7) m2 -= 7;
                int m3 = m2 + 1; if (m3 >= 7) m3 -= 7;
                const float hb = (float)(h4 * 4);
                float4 o;
                o.x = fmaf(T, hb + 1.0f, L) + stp[m0];
                o.y = fmaf(T, hb + 2.0f, L) + stp[m1];
                o.z = fmaf(T, hb + 3.0f, L) + stp[m2];
                o.w = fmaf(T, hb + 4.0f, L) + stp[m3];
                prb[q] = o;
            }
            // advance q += 256: h4 += 4 (mod 14), s += 18 (+carry), m0 += 2 (mod 7)
            h4 += 4; s += 18;
            if (h4 >= 14) { h4 -= 14; s += 1; }
            if (s >= 129) { s -= 129; row += 1; }
            m0 += 2; if (m0 >= 7) m0 -= 7;
        }
    }
}

extern "C" void kernel_launch(void* const* d_in, const int* in_sizes, int n_in,
                              void* d_out, int out_size, void* d_ws, size_t ws_size,
                              hipStream_t stream) {
    const float* query  = (const float*)d_in[0];
    const float* params = (const float*)d_in[1];

    float* out   = (float*)d_out;
    float* sm    = out;                                  // 4096*1024
    float* pr    = out + (size_t)NROWS * TLEN;           // 4096*129*56
    float* diffs = pr  + (size_t)NROWS * 129 * 56;       // 4096

    hipLaunchKernelGGL(es_fused, dim3(NROWS / RPB), dim3(256), 0, stream,
                       query, params, sm, diffs, (float4*)pr);
}

// Round 9
// 34.765 us; speedup vs baseline: 1.4428x; 1.0281x over previous
//
#include <hip/hip_runtime.h>
#include <cmath>

#define NROWS 4096
#define TLEN  1024
#define RPB   8            // rows per block
#define LT0   895
#define ST0   889
#define LTN   129
#define STN   135
#define PRV4R 1806         // float4 per row of pr = 129*56/4
#define PRV4B (RPB * PRV4R)   // 14448

__device__ __forceinline__ float sigmoidf_(float x) {
    return 1.0f / (1.0f + expf(-x));
}

__device__ __forceinline__ float f4c(const float4& v, int k) {
    switch (k & 3) { case 0: return v.x; case 1: return v.y; case 2: return v.z; default: return v.w; }
}

// One block = 8 rows x 32 chunks of 32 timesteps, 512 threads.
// Threads 0..255 run the blocked parallel scan (LB linear 2x2 recurrence +
// 7 seasonal lag-1 chains); threads 256..511 join only for the memory-burst
// phases (query stage-in, sm drain, pr drain) to double drain-phase TLP.
__global__ __launch_bounds__(512, 4)
void es_fused(const float* __restrict__ query,
              const float* __restrict__ params,
              float* __restrict__ sm,
              float* __restrict__ diffs,
              float4* __restrict__ pr4)
{
    __shared__ float4 ystage[RPB * 256];   // 32KB: query in, then sm out
    __shared__ float lds_P[RPB * 65];      // r*65 + 2k + b
    __shared__ float lds_start[RPB * 65];
    __shared__ float lds_q[RPB * 225];     // r*225 + k*7 + g (global phase)
    __shared__ float lds_dsum[RPB * 33];
    __shared__ float lds_par[RPB * 16];    // {L0,B0,ia,A10,A11,ic,is[7]}
    __shared__ float Ltl[RPB * 132];       // level  t=895..1023
    __shared__ float Ttl[RPB * 132];       // trend  t=895..1023
    __shared__ float Stl[RPB * 136];       // seas   t=889..1023

    const int tid = threadIdx.x;
    const int base = blockIdx.x * RPB;
    const int r = (tid >> 5) & 7;    // meaningful for tid < 256
    const int k = tid & 31;
    const int n = base + r;

    // ---- phase 0: coalesced query stage -> LDS (swizzled), all 512 ----
    {
        const float4* qb = reinterpret_cast<const float4*>(query + (size_t)base * TLEN);
        #pragma unroll
        for (int i = 0; i < 4; ++i) {
            const int w = i * 512 + tid;
            ystage[(w & ~7) | ((w ^ (w >> 3)) & 7)] = qb[w];
        }
    }

    float a = 0.f, b = 0.f, c = 0.f, ia = 0.f, ib = 0.f, ic = 0.f;
    if (tid < 256) {
        const float* pp = params + (size_t)n * 12;
        a  = sigmoidf_(pp[1]);
        b  = sigmoidf_(pp[3]);
        c  = pp[4];                   // raw (reference does NOT sigmoid)
        ia = 1.0f - a; ib = 1.0f - b; ic = 1.0f - c;
        if (k == 0) {
            float* par = &lds_par[r * 16];
            par[0] = pp[0];                  // L0
            par[1] = pp[2];                  // B0
            par[2] = ia;                     // A00 = A01
            par[3] = -(a * b);               // A10
            par[4] = ib + b * ia;            // A11
            par[5] = ic;
            #pragma unroll
            for (int l = 0; l < 7; ++l) par[6 + l] = sigmoidf_(pp[5 + l]);
        }
    }
    __syncthreads();

    float4 yv[8];
    float e[32];
    float st0 = 0.f, st1 = 0.f;

    // ---- phase 1: per-thread y chunk + affine partial (zero init) ----
    if (tid < 256) {
        const int ksw = k & 7;
        #pragma unroll
        for (int i = 0; i < 8; ++i)
            yv[i] = ystage[r * 256 + ((k * 8 + i) ^ ksw)];

        float L = 0.0f, B = 0.0f;
        #pragma unroll
        for (int j = 0; j < 32; ++j) {
            const float yy = f4c(yv[j >> 2], j);
            const float pred  = L + B;
            const float level = fmaf(a, yy, ia * pred);
            const float trend = fmaf(b, level - L, ib * B);
            L = level; B = trend;
        }
        lds_P[r * 65 + 2 * k]     = L;
        lds_P[r * 65 + 2 * k + 1] = B;
    }
    __syncthreads();

    // ---- phase 2: per-row serial scan of 32 chunk summaries (8 threads) ----
    if (tid < 8) {
        const float* par = &lds_par[tid * 16];
        float m00 = par[2], m01 = par[2], m10 = par[3], m11 = par[4];
        #pragma unroll
        for (int s = 0; s < 5; ++s) {    // M = A^32
            const float t00 = m00 * m00 + m01 * m10;
            const float t01 = m00 * m01 + m01 * m11;
            const float t10 = m10 * m00 + m11 * m10;
            const float t11 = m10 * m01 + m11 * m11;
            m00 = t00; m01 = t01; m10 = t10; m11 = t11;
        }
        float P0[32], P1[32];
        #pragma unroll
        for (int kk = 0; kk < 32; ++kk) {
            P0[kk] = lds_P[tid * 65 + 2 * kk];
            P1[kk] = lds_P[tid * 65 + 2 * kk + 1];
        }
        float s0 = par[0], s1 = par[1];
        #pragma unroll
        for (int kk = 0; kk < 32; ++kk) {
            lds_start[tid * 65 + 2 * kk]     = s0;
            lds_start[tid * 65 + 2 * kk + 1] = s1;
            const float t0 = m00 * s0 + m01 * s1 + P0[kk];
            const float t1 = m10 * s0 + m11 * s1 + P1[kk];
            s0 = t0; s1 = t1;
        }
    }
    __syncthreads();

    // ---- phase 3: true chain once; save e[]; partials; |dL|; L/T tails ----
    if (tid < 256) {
        st0 = lds_start[r * 65 + 2 * k];
        st1 = lds_start[r * 65 + 2 * k + 1];
        float L = st0, B = st1, dsum = 0.0f;
        float q[7] = {0,0,0,0,0,0,0};
        #pragma unroll
        for (int j = 0; j < 32; ++j) {
            const float yy = f4c(yv[j >> 2], j);
            const float pred  = L + B;
            const float level = fmaf(a, yy, ia * pred);
            const float d     = level - L;
            dsum += fabsf(d);
            const float trend = fmaf(b, d, ib * B);
            const float ee    = yy - pred;
            e[j] = ee;
            q[j % 7] = fmaf(ic, q[j % 7], c * ee);
            L = level; B = trend;
        }
        const int kp = (4 * k) % 7;      // global phase of local slot 0
        #pragma unroll
        for (int l = 0; l < 7; ++l) {
            int g = kp + l; if (g >= 7) g -= 7;
            lds_q[r * 225 + k * 7 + g] = q[l];
        }
        lds_dsum[r * 33 + k] = dsum;

        // phase 3b: k>=27 lanes rebuild level/trend tails -> LDS
        if (k >= 27) {
            float prevL = st0, Bv = st1;
            #pragma unroll
            for (int j = 0; j < 32; ++j) {
                const float level = f4c(yv[j >> 2], j) - ia * e[j];
                const float trend = fmaf(b, level - prevL, ib * Bv);
                const int tg = k * 32 + j;
                if (tg >= LT0) {
                    Ltl[r * 132 + tg - LT0] = level;
                    Ttl[r * 132 + tg - LT0] = trend;
                }
                prevL = level; Bv = trend;
            }
        }
    }
    __syncthreads();

    // ---- phase 4: seasonal chain scan (56 threads) + diffs reduce (8) ----
    if (tid < 56) {
        const int rr = tid / 7, p = tid % 7;
        const float icc = lds_par[rr * 16 + 5];
        const float ic2 = icc * icc;
        const float ic4 = ic2 * ic2;
        const float ic5 = ic4 * icc;
        float v = lds_par[rr * 16 + 6 + p];
        float qq[32];
        #pragma unroll
        for (int kk = 0; kk < 32; ++kk) qq[kk] = lds_q[rr * 225 + kk * 7 + p];
        int l = p;
        #pragma unroll
        for (int kk = 0; kk < 32; ++kk) {
            const float m = (l < 4) ? ic5 : ic4;   // occurrences of phase in chunk
            const float nv = fmaf(m, v, qq[kk]);
            lds_q[rr * 225 + kk * 7 + p] = v;      // phase value entering chunk kk
            v = nv;
            l += 3; if (l >= 7) l -= 7;            // local slot of p in next chunk
        }
    } else if (tid < 64) {
        const int rr = tid - 56;
        float s = 0.0f;
        #pragma unroll
        for (int kk = 0; kk < 32; ++kk) s += lds_dsum[rr * 33 + kk];
        diffs[blockIdx.x * RPB + rr] = s * (1.0f / 1024.0f);
    }
    __syncthreads();

    // ---- phase 5: lag-1 sn chain; smv = ia*e - sn -> swizzled LDS; S tails ----
    if (tid < 256) {
        float sg[7];
        const int kp = (4 * k) % 7;
        #pragma unroll
        for (int l = 0; l < 7; ++l) {
            int g = kp + l; if (g >= 7) g -= 7;
            sg[l] = lds_q[r * 225 + k * 7 + g];
        }
        const int ksw = k & 7;
        float4 ov;
        #pragma unroll
        for (int j = 0; j < 32; ++j) {
            const float sn = fmaf(ic, sg[j % 7], c * e[j]);
            sg[j % 7] = sn;
            const float smv = ia * e[j] - sn;
            e[j] = sn;
            switch (j & 3) { case 0: ov.x = smv; break; case 1: ov.y = smv; break;
                             case 2: ov.z = smv; break; default: ov.w = smv; }
            if ((j & 3) == 3)
                ystage[r * 256 + ((k * 8 + (j >> 2)) ^ ksw)] = ov;
        }
        if (k >= 27) {
            #pragma unroll
            for (int j = 0; j < 32; ++j) {
                const int tg = k * 32 + j;
                if (tg >= ST0) Stl[r * 136 + tg - ST0] = e[j];
            }
        }
    }
    __syncthreads();

    // ---- phase 6a: coalesced sm drain from LDS (all 512) ----
    {
        float4* smb = reinterpret_cast<float4*>(sm + (size_t)base * TLEN);
        #pragma unroll
        for (int i = 0; i < 4; ++i) {
            const int w = i * 512 + tid;
            smb[w] = ystage[(w & ~7) | ((w ^ (w >> 3)) & 7)];
        }
    }

    // ---- phase 6b: pure pr drain from LDS tails (all 512, independent iters) ----
    {
        float4* prb = pr4 + (size_t)blockIdx.x * PRV4B;
        #pragma unroll 4
        for (int i = 0; i < 28; ++i) {
            const int q = i * 512 + tid;
            const int row = q / PRV4R;
            const int rem = q - row * PRV4R;
            const int s   = rem / 14;
            const int h4  = rem - s * 14;
            const float L = Ltl[row * 132 + s];
            const float T = Ttl[row * 132 + s];
            const float* stp = &Stl[row * 136 + s];
            const int hb = h4 * 4;
            int m0 = hb % 7;
            int m1 = m0 + 1; if (m1 >= 7) m1 -= 7;
            int m2 = m1 + 1; if (m2 >= 7) m2 -= 7;
            int m3 = m2 + 1; if (m3 >= 7) m3 -= 7;
            const float hbf = (float)hb;
            float4 o;
            o.x = fmaf(T, hbf + 1.0f, L) + stp[m0];
            o.y = fmaf(T, hbf + 2.0f, L) + stp[m1];
            o.z = fmaf(T, hbf + 3.0f, L) + stp[m2];
            o.w = fmaf(T, hbf + 4.0f, L) + stp[m3];
            prb[q] = o;
        }
        const int q = 28 * 512 + tid;
        if (q < PRV4B) {
            const int row = q / PRV4R;
            const int rem = q - row * PRV4R;
            const int s   = rem / 14;
            const int h4  = rem - s * 14;
            const float L = Ltl[row * 132 + s];
            const float T = Ttl[row * 132 + s];
            const float* stp = &Stl[row * 136 + s];
            const int hb = h4 * 4;
            int m0 = hb % 7;
            int m1 = m0 + 1; if (m1 >= 7) m1 -= 7;
            int m2 = m1 + 1; if (m2 >= 7) m2 -= 7;
            int m3 = m2 + 1; if (m3 >= 7) m3 -= 7;
            const float hbf = (float)hb;
            float4 o;
            o.x = fmaf(T, hbf + 1.0f, L) + stp[m0];
            o.y = fmaf(T, hbf + 2.0f, L) + stp[m1];
            o.z = fmaf(T, hbf + 3.0f, L) + stp[m2];
            o.w = fmaf(T, hbf + 4.0f, L) + stp[m3];
            prb[q] = o;
        }
    }
}

extern "C" void kernel_launch(void* const* d_in, const int* in_sizes, int n_in,
                              void* d_out, int out_size, void* d_ws, size_t ws_size,
                              hipStream_t stream) {
    const float* query  = (const float*)d_in[0];
    const float* params = (const float*)d_in[1];

    float* out   = (float*)d_out;
    float* sm    = out;                                  // 4096*1024
    float* pr    = out + (size_t)NROWS * TLEN;           // 4096*129*56
    float* diffs = pr  + (size_t)NROWS * 129 * 56;       // 4096

    hipLaunchKernelGGL(es_fused, dim3(NROWS / RPB), dim3(512), 0, stream,
                       query, params, sm, diffs, (float4*)pr);
}